// Round 3
// baseline (296.421 us; speedup 1.0000x reference)
//
#include <hip/hip_runtime.h>
#include <math.h>

#define B_ 4
#define T_ 4096
#define D_ 2048
#define CT 16
#define NC (T_ / CT)      // 256 chunks per batch
#define NG 16             // scan groups per (b,d) channel
#define GC (NC / NG)      // 16 chunks per group

__device__ __forceinline__ float fast_rcp(float x) { return __builtin_amdgcn_rcpf(x); }

// tanh(u) = 1 - 2/(e^{2u}+1), div replaced by v_rcp
__device__ __forceinline__ float fast_tanh(float u) {
    float e = __expf(2.0f * u);
    return 1.0f - 2.0f * fast_rcp(e + 1.0f);
}

// 0.5*x*(1+tanh(u)) == x - x/(exp(2u)+1)  -> 1 exp + 1 rcp + few fma
__device__ __forceinline__ float gelu_tanh(float x) {
    const float c = 0.7978845608028654f;  // sqrt(2/pi)
    float u = c * x * fmaf(0.044715f, x * x, 1.0f);
    float e = __expf(2.0f * u);
    return x - x * fast_rcp(e + 1.0f);
}

// K1: per (b, chunk) chunk-local sums of x, x^2, gelu(x) per channel.
// Grid: B*NC = 1024 blocks -> 4 blocks/CU.
__global__ __launch_bounds__(256) void k1_partials(
        const float* __restrict__ x,
        float* __restrict__ px, float* __restrict__ pxx, float* __restrict__ po) {
    int bid = blockIdx.x;
    int b = bid / NC, c = bid % NC;
    int tid = threadIdx.x;
    int d0 = tid * 8;
    float sx[8], sxx[8], so[8];
#pragma unroll
    for (int i = 0; i < 8; i++) { sx[i] = 0.f; sxx[i] = 0.f; so[i] = 0.f; }

    const float* base = x + ((size_t)(b * T_ + c * CT)) * D_ + d0;
    for (int t = 0; t < CT; t++) {
        float4 v0 = *(const float4*)(base);
        float4 v1 = *(const float4*)(base + 4);
        float v[8] = {v0.x, v0.y, v0.z, v0.w, v1.x, v1.y, v1.z, v1.w};
#pragma unroll
        for (int i = 0; i < 8; i++) {
            sx[i]  += v[i];
            sxx[i]  = fmaf(v[i], v[i], sxx[i]);
            so[i]  += gelu_tanh(v[i]);
        }
        base += D_;
    }
    size_t pidx = (size_t)(b * NC + c) * D_ + d0;
    *(float4*)(px  + pidx)     = make_float4(sx[0], sx[1], sx[2], sx[3]);
    *(float4*)(px  + pidx + 4) = make_float4(sx[4], sx[5], sx[6], sx[7]);
    *(float4*)(pxx + pidx)     = make_float4(sxx[0], sxx[1], sxx[2], sxx[3]);
    *(float4*)(pxx + pidx + 4) = make_float4(sxx[4], sxx[5], sxx[6], sxx[7]);
    *(float4*)(po  + pidx)     = make_float4(so[0], so[1], so[2], so[3]);
    *(float4*)(po  + pidx + 4) = make_float4(so[4], so[5], so[6], so[7]);
}

// K2a: per (b, group, d) sum the group's 16 chunk-partials -> group totals.
// B*NG*D = 131072 threads = 512 blocks.
__global__ __launch_bounds__(256) void k2a_group_sums(
        const float* __restrict__ px, const float* __restrict__ pxx,
        const float* __restrict__ po,
        float* __restrict__ gx, float* __restrict__ gxx, float* __restrict__ go) {
    int gid = blockIdx.x * 256 + threadIdx.x;
    int d = gid & (D_ - 1);
    int g = (gid >> 11) & (NG - 1);
    int b = gid >> 15;
    size_t base = ((size_t)(b * NC + g * GC)) * D_ + d;
    float sx = 0.f, sxx = 0.f, so = 0.f;
#pragma unroll
    for (int j = 0; j < GC; j++) {
        sx  += px [base + (size_t)j * D_];
        sxx += pxx[base + (size_t)j * D_];
        so  += po [base + (size_t)j * D_];
    }
    size_t gi = ((size_t)(b * NG + g)) * D_ + d;
    gx[gi] = sx; gxx[gi] = sxx; go[gi] = so;
}

// K2c: per (b, group, d): exclusive offset from previous groups' totals
// (<=15 L2-hot loads), then serial in-place exclusive scan of the group's
// 16 chunk partials. 512 blocks.
__global__ __launch_bounds__(256) void k2c_scan(
        float* __restrict__ px, float* __restrict__ pxx, float* __restrict__ po,
        const float* __restrict__ gx, const float* __restrict__ gxx,
        const float* __restrict__ go) {
    int gid = blockIdx.x * 256 + threadIdx.x;
    int d = gid & (D_ - 1);
    int g = (gid >> 11) & (NG - 1);   // uniform within a block
    int b = gid >> 15;

    float ox = 0.f, oxx = 0.f, oo = 0.f;
    for (int g2 = 0; g2 < g; g2++) {
        size_t gi = ((size_t)(b * NG + g2)) * D_ + d;
        ox += gx[gi]; oxx += gxx[gi]; oo += go[gi];
    }
    size_t base = ((size_t)(b * NC + g * GC)) * D_ + d;
#pragma unroll
    for (int j = 0; j < GC; j++) {
        float tx = px[base], txx = pxx[base], to = po[base];
        px[base] = ox; pxx[base] = oxx; po[base] = oo;
        ox += tx; oxx += txx; oo += to;
        base += D_;
    }
}

// K3: per (b, chunk) serial walk over CT=16 timesteps, batched W=4 per
// reduction round. Grid: 1024 blocks -> 4 blocks/CU, 16 waves/CU.
__global__ __launch_bounds__(256) void k3_main(
        const float* __restrict__ x,
        const float* __restrict__ px, const float* __restrict__ pxx,
        const float* __restrict__ po,
        const float* __restrict__ p_log_tau,
        const float* __restrict__ p_log_sigma_raw,
        const float* __restrict__ p_log_w_raw,
        float* __restrict__ y) {
    __shared__ float red[4 * 16];
    __shared__ float gates[4];

    int bid = blockIdx.x;
    int b = bid / NC, c = bid % NC;
    int tid = threadIdx.x;
    int d0 = tid * 8;

    float tau   = __expf(p_log_tau[0]);
    float sigma = log1pf(__expf(p_log_sigma_raw[0]));
    float w     = log1pf(__expf(p_log_w_raw[0]));

    float cx[8], cxx[8], co[8];
    size_t pidx = (size_t)(b * NC + c) * D_ + d0;
    {
        float4 a0 = *(const float4*)(px  + pidx);
        float4 a1 = *(const float4*)(px  + pidx + 4);
        float4 b0 = *(const float4*)(pxx + pidx);
        float4 b1 = *(const float4*)(pxx + pidx + 4);
        float4 c0 = *(const float4*)(po  + pidx);
        float4 c1 = *(const float4*)(po  + pidx + 4);
        cx[0]=a0.x; cx[1]=a0.y; cx[2]=a0.z; cx[3]=a0.w;
        cx[4]=a1.x; cx[5]=a1.y; cx[6]=a1.z; cx[7]=a1.w;
        cxx[0]=b0.x; cxx[1]=b0.y; cxx[2]=b0.z; cxx[3]=b0.w;
        cxx[4]=b1.x; cxx[5]=b1.y; cxx[6]=b1.z; cxx[7]=b1.w;
        co[0]=c0.x; co[1]=c0.y; co[2]=c0.z; co[3]=c0.w;
        co[4]=c1.x; co[5]=c1.y; co[6]=c1.z; co[7]=c1.w;
    }

    const float* xb = x + ((size_t)(b * T_ + c * CT)) * D_ + d0;
    float*       yb = y + ((size_t)(b * T_ + c * CT)) * D_ + d0;

    for (int r = 0; r < CT / 4; r++) {
        float acc[16];
#pragma unroll
        for (int k = 0; k < 16; k++) acc[k] = 0.f;
        float o[4][8];

#pragma unroll
        for (int t = 0; t < 4; t++) {
            int tg = c * CT + r * 4 + t;
            float inv = fast_rcp((float)(tg + 1));
            const float* xr = xb + (size_t)(r * 4 + t) * D_;
            float4 v0 = *(const float4*)(xr);
            float4 v1 = *(const float4*)(xr + 4);
            float v[8] = {v0.x, v0.y, v0.z, v0.w, v1.x, v1.y, v1.z, v1.w};
#pragma unroll
            for (int i = 0; i < 8; i++) {
                float vv = v[i];
                float oo = gelu_tanh(vv);
                o[t][i] = oo;
                float mu = cx[i] * inv;
                float sq = cxx[i] * inv;
                float var = fmaxf(fmaf(-mu, mu, sq), 1e-4f);
                float stde = __builtin_amdgcn_sqrtf(var) + 1e-5f;
                float z = (vv - mu) * fast_rcp(stde);
                acc[t * 4 + 0] += fabsf(z);
                float mo = co[i] * inv;
                acc[t * 4 + 1] = fmaf(oo, mo, acc[t * 4 + 1]);
                acc[t * 4 + 2] = fmaf(oo, oo, acc[t * 4 + 2]);
                acc[t * 4 + 3] = fmaf(mo, mo, acc[t * 4 + 3]);
                cx[i] += vv;
                cxx[i] = fmaf(vv, vv, cxx[i]);
                co[i] += oo;
            }
        }

        // wave reduce: 16 independent chains -> pipelined cross-lane ops
#pragma unroll
        for (int off = 32; off >= 1; off >>= 1) {
#pragma unroll
            for (int k = 0; k < 16; k++) acc[k] += __shfl_down(acc[k], off);
        }

        __syncthreads();   // previous round's red/gates consumers are done
        if ((tid & 63) == 0) {
            int wbase = (tid >> 6) * 16;
#pragma unroll
            for (int k = 0; k < 16; k++) red[wbase + k] = acc[k];
        }
        __syncthreads();
        if (tid < 4) {
            int t = tid;
            float s0 = 0.f, s1 = 0.f, s2 = 0.f, s3 = 0.f;
#pragma unroll
            for (int wv = 0; wv < 4; wv++) {
                s0 += red[wv * 16 + t * 4 + 0];
                s1 += red[wv * 16 + t * 4 + 1];
                s2 += red[wv * 16 + t * 4 + 2];
                s3 += red[wv * 16 + t * 4 + 3];
            }
            int tg = c * CT + r * 4 + t;
            float mask = (tg >= 1) ? 1.0f : 0.0f;
            float mabs = s0 * (1.0f / (float)D_) * mask;
            float denom = fmaxf(sqrtf(s2), 1e-12f) * fmaxf(sqrtf(s3), 1e-12f);
            float cosv = (s1 * fast_rcp(denom)) * mask;
            gates[t] = __expf(-tau * cosv) * (1.0f + w * fast_tanh(sigma * mabs));
        }
        __syncthreads();

#pragma unroll
        for (int t = 0; t < 4; t++) {
            float g = gates[t];
            float* yr = yb + (size_t)(r * 4 + t) * D_;
            *(float4*)(yr)     = make_float4(o[t][0]*g, o[t][1]*g, o[t][2]*g, o[t][3]*g);
            *(float4*)(yr + 4) = make_float4(o[t][4]*g, o[t][5]*g, o[t][6]*g, o[t][7]*g);
        }
    }
}

extern "C" void kernel_launch(void* const* d_in, const int* in_sizes, int n_in,
                              void* d_out, int out_size, void* d_ws, size_t ws_size,
                              hipStream_t stream) {
    const float* x   = (const float*)d_in[0];
    const float* lt  = (const float*)d_in[1];
    const float* lsr = (const float*)d_in[2];
    const float* lwr = (const float*)d_in[3];
    float* y = (float*)d_out;

    const size_t npart = (size_t)B_ * NC * D_;      // 2,097,152 floats each
    const size_t ngrp  = (size_t)B_ * NG * D_;      // 131,072 floats each
    float* px  = (float*)d_ws;
    float* pxx = px  + npart;
    float* po  = pxx + npart;
    float* gx  = po  + npart;
    float* gxx = gx  + ngrp;
    float* go  = gxx + ngrp;
    // total ws: 3*8MiB + 3*512KiB = 25.5 MiB

    k1_partials<<<B_ * NC, 256, 0, stream>>>(x, px, pxx, po);
    k2a_group_sums<<<(B_ * NG * D_) / 256, 256, 0, stream>>>(px, pxx, po, gx, gxx, go);
    k2c_scan<<<(B_ * NG * D_) / 256, 256, 0, stream>>>(px, pxx, po, gx, gxx, go);
    k3_main<<<B_ * NC, 256, 0, stream>>>(x, px, pxx, po, lt, lsr, lwr, y);
}